// Round 16
// baseline (10492.930 us; speedup 1.0000x reference)
//
#include <hip/hip_runtime.h>
#include <hip/hip_fp16.h>

#define SEQ   1024
#define TLEN  1024
#define NB_B  4
#define NTHR  512
#define SLICE 3072

// d_out float map (786,432 floats):
//  [0,114688)       fp16 transposed weights (229376 halves, prep_t)
//  [114688,180224)  h0 ring slot0 [128 pairs][512]
//  [180224,245760)  h0 ring slot1
//  [688128,753664)  h0 ring slot2          (stash ends 686592; flags start 753664)
//  [753664,770048)  flags: flag0[p] @ +p*64, flagC[p] @ +8192+p*64 (memset 0)
//  slices 96..223 @ offset [1024,1536): final-h stash = floats [295936,686592)
// Weight HALF-index offsets (within half-array at d_out base):
#define WT0IH 0
#define WT0HH 32768
#define WT1IH 98304
#define WT1HH 163840
#define WTOT  229376
#define RINGA 114688
#define RINGB 180224
#define RINGC 688128
#define FLAGF 753664

__device__ __forceinline__ float sig1(float x)  { return 1.0f / (1.0f + __expf(-x)); }
__device__ __forceinline__ float tanh1(float x) { return 1.0f - 2.0f / (__expf(2.0f * x) + 1.0f); }

__device__ __forceinline__ void astoref(float* pp, float v) {
  __hip_atomic_store(pp, v, __ATOMIC_RELAXED, __HIP_MEMORY_SCOPE_AGENT);
}
__device__ __forceinline__ float aloadf(const float* pp) {
  return __hip_atomic_load(pp, __ATOMIC_RELAXED, __HIP_MEMORY_SCOPE_AGENT);
}
__device__ __forceinline__ void astoreu(unsigned* pp, unsigned v) {
  __hip_atomic_store(pp, v, __ATOMIC_RELAXED, __HIP_MEMORY_SCOPE_AGENT);
}
__device__ __forceinline__ unsigned aloadu(const unsigned* pp) {
  return __hip_atomic_load(pp, __ATOMIC_RELAXED, __HIP_MEMORY_SCOPE_AGENT);
}
__device__ __forceinline__ int rbase(int sl) {   // ring slot -> d_out float offset
  return (sl == 2) ? RINGC : (RINGA + sl * 65536);
}

// One-time weight transpose+cast: [row][k] fp32 -> fp16 [k>>2][row][k&3] in d_out
extern "C" __global__ void __launch_bounds__(256)
prep_t(const float* __restrict__ Wih0, const float* __restrict__ Whh0,
       const float* __restrict__ Wih1, const float* __restrict__ Whh1,
       __half* __restrict__ wt16) {
  const int idx = blockIdx.x * 256 + threadIdx.x;
  if (idx >= WTOT) return;
  float v; int r, k, base;
  if (idx < 32768)      { r = idx >> 6;  k = idx & 63;                  v = Wih0[idx]; base = WT0IH; }
  else if (idx < 98304) { int j = idx - 32768;  r = j >> 7; k = j & 127; v = Whh0[j];  base = WT0HH; }
  else if (idx < 163840){ int j = idx - 98304;  r = j >> 7; k = j & 127; v = Wih1[j];  base = WT1IH; }
  else                  { int j = idx - 163840; r = j >> 7; k = j & 127; v = Whh1[j];  base = WT1HH; }
  wt16[base + (((k >> 2) * 512 + r) << 2) + (k & 3)] = __float2half(v);
}

// fp16 weight quad -> two float2
#define WCVT(wp, wa, wb)                                                    \
  float2 wa = __half22float2(*reinterpret_cast<const __half2*>(&(wp).x));   \
  float2 wb = __half22float2(*reinterpret_cast<const __half2*>(&(wp).y));

// Paired pipeline (r15 structure), weights held in REGISTERS for all 1024 steps.
// blocks 0..127 = layer0 for batches 4p..4p+3; blocks 128..255 = layer1 same
// batches ~2 steps behind. Ring depth 3, register-prefetched h0, 2 syncs/step.
extern "C" __global__ void __launch_bounds__(NTHR, 2)
lstm_pair(const float* __restrict__ X1, const float* __restrict__ X2,
          const float* __restrict__ W1m, const float* __restrict__ b1m,
          const float* __restrict__ bih0, const float* __restrict__ bhh0,
          const float* __restrict__ bih1, const float* __restrict__ bhh1,
          const float* wt, float* out) {
  __shared__ float hbuf[NB_B * 320];   // per batch: feat[64] | h0[128] | h1[128]
  __shared__ float gacc[NB_B * 512];   // [batch][gate-row]  (conflict-free)

  const int tid = threadIdx.x;
  const int bid = blockIdx.x;
  const bool L1role = bid >= 128;
  const int p  = L1role ? bid - 128 : bid;
  const int r  = tid;                  // gate row 0..511
  const int u  = tid & 127;            // hidden unit
  const int bp = tid >> 7;             // batch slot 0..3

  const __half* wt16 = (const __half*)wt;
  unsigned* flag0 = (unsigned*)(out + FLAGF) + p * 64;          // L0 progress
  unsigned* flagC = (unsigned*)(out + FLAGF) + 8192 + p * 64;   // L1 consumed

  for (int i = tid; i < NB_B * 320; i += NTHR) hbuf[i] = 0.0f;
  __syncthreads();

  if (!L1role) {
    // ---------------- layer-0 producer ----------------
    const int m  = tid & 63;           // mlp1 unit
    const int bf = tid >> 6;           // mlp1 batch slot (active if < NB_B)
    float w1r[5]; float b1r = 0.0f;
    const float* xptr = X1;
    if (bf < NB_B) {
      #pragma unroll
      for (int i = 0; i < 5; ++i) w1r[i] = W1m[m * 5 + i];
      b1r = b1m[m];
      const int ebx = p * NB_B + bf;
      xptr = (ebx < 256) ? (X1 + (size_t)ebx * SEQ * 5)
                         : (X2 + (size_t)(ebx - 256) * SEQ * 5);
    }
    const float bias0 = bih0[r] + bhh0[r];

    // ---- one-time weight preload into REGISTERS (96 VGPR) ----
    uint2 wih_r[16], whh_r[32];
    {
      const uint2* wih0 = (const uint2*)(wt16 + WT0IH) + r;
      const uint2* whh0 = (const uint2*)(wt16 + WT0HH) + r;
      #pragma unroll
      for (int kc = 0; kc < 16; ++kc) wih_r[kc] = wih0[kc * 512];
      #pragma unroll
      for (int kc = 0; kc < 32; ++kc) whh_r[kc] = whh0[kc * 512];
    }

    // prologue: feat[0]
    if (bf < NB_B) {
      float s = b1r;
      #pragma unroll
      for (int i = 0; i < 5; ++i) s = fmaf(w1r[i], xptr[i], s);
      hbuf[bf * 320 + m] = fmaxf(s, 0.0f);
    }
    __syncthreads();

    float c0 = 0.0f;
    int sl = 0;                        // slot(t)
    unsigned fcs = 0;                  // cached flagC (monotonic)
    for (int t = 0; t < SEQ; ++t) {
      // slot-reuse guard: L1 must have consumed h0[t-3] (tid0; post-gates sync
      // orders every thread's ring store after this poll)
      if (tid == 0 && t >= 3) {
        const unsigned tgt = (unsigned)(t - 2);
        while (fcs < tgt) {
          fcs = aloadu(flagC);
          if (fcs < tgt) __builtin_amdgcn_s_sleep(2);
        }
      }

      {  // layer0 gate rows: Wih0.feat[t] + Whh0.h0[t-1]  (weights from registers)
        float acc[NB_B];
        #pragma unroll
        for (int b = 0; b < NB_B; ++b) acc[b] = bias0;
        #pragma unroll
        for (int kc = 0; kc < 16; ++kc) {
          WCVT(wih_r[kc], wa, wb)
          #pragma unroll
          for (int b = 0; b < NB_B; ++b) {
            float4 hv = *(const float4*)&hbuf[b * 320 + kc * 4];
            acc[b] = fmaf(wa.x, hv.x, fmaf(wa.y, hv.y,
                     fmaf(wb.x, hv.z, fmaf(wb.y, hv.w, acc[b]))));
          }
        }
        #pragma unroll
        for (int kc = 0; kc < 32; ++kc) {
          WCVT(whh_r[kc], wa, wb)
          #pragma unroll
          for (int b = 0; b < NB_B; ++b) {
            float4 hv = *(const float4*)&hbuf[b * 320 + 64 + kc * 4];
            acc[b] = fmaf(wa.x, hv.x, fmaf(wa.y, hv.y,
                     fmaf(wb.x, hv.z, fmaf(wb.y, hv.w, acc[b]))));
          }
        }
        gacc[0 * 512 + r] = acc[0];
        gacc[1 * 512 + r] = acc[1];
        gacc[2 * 512 + r] = acc[2];
        gacc[3 * 512 + r] = acc[3];
      }
      __syncthreads();                 // gacc ready; hbuf reads done; poll done

      // update -> h0[t] (LDS + ring publish) ; feat[t+1]
      {
        const float* gb = &gacc[bp * 512];
        float gi = gb[u], gf = gb[128 + u], gg = gb[256 + u], go = gb[384 + u];
        float cc = sig1(gf) * c0 + sig1(gi) * tanh1(gg);
        c0 = cc;
        float hv = sig1(go) * tanh1(cc);
        hbuf[bp * 320 + 64 + u] = hv;
        astoref(out + rbase(sl) + p * 512 + tid, hv);
      }
      if (bf < NB_B && t + 1 < SEQ) {
        const float* x = xptr + (size_t)(t + 1) * 5;
        float s = b1r;
        s = fmaf(w1r[0], x[0], s); s = fmaf(w1r[1], x[1], s);
        s = fmaf(w1r[2], x[2], s); s = fmaf(w1r[3], x[3], s);
        s = fmaf(w1r[4], x[4], s);
        hbuf[bf * 320 + m] = fmaxf(s, 0.0f);
      }
      __syncthreads();                 // ring stores drained (vmcnt0) + LDS ready
      if (tid == 0) astoreu(flag0, (unsigned)(t + 1));
      if (++sl == 3) sl = 0;
    }
  } else {
    // ---------------- layer-1 consumer ----------------
    const float bias1 = bih1[r] + bhh1[r];

    // ---- one-time weight preload into REGISTERS (128 VGPR) ----
    uint2 wih_r[32], whh_r[32];
    {
      const uint2* wih1 = (const uint2*)(wt16 + WT1IH) + r;
      const uint2* whh1 = (const uint2*)(wt16 + WT1HH) + r;
      #pragma unroll
      for (int kc = 0; kc < 32; ++kc) wih_r[kc] = wih1[kc * 512];
      #pragma unroll
      for (int kc = 0; kc < 32; ++kc) whh_r[kc] = whh1[kc * 512];
    }

    // prologue: stage h0[0]
    {
      unsigned f0 = aloadu(flag0);
      while (f0 < 1u) { __builtin_amdgcn_s_sleep(2); f0 = aloadu(flag0); }
      hbuf[bp * 320 + 64 + u] = aloadf(out + RINGA + p * 512 + tid);
    }
    __syncthreads();

    float c1 = 0.0f;
    int sl = 1;                        // slot(s+1)
    unsigned f0s = 0;                  // cached flag0 (monotonic)
    for (int s = 0; s < SEQ; ++s) {
      // prefetch h0[s+1] into a register; latency hidden under gates
      float rv = 0.0f;
      const bool pf = (s + 1 < SEQ);
      if (pf) {
        const unsigned tgt = (unsigned)(s + 2);
        while (f0s < tgt) {
          f0s = aloadu(flag0);
          if (f0s < tgt) __builtin_amdgcn_s_sleep(2);
        }
        rv = aloadf(out + rbase(sl) + p * 512 + tid);
      }

      {  // layer1 gate rows: Wih1.h0[s] + Whh1.h1[s-1]  (weights from registers)
        float acc[NB_B];
        #pragma unroll
        for (int b = 0; b < NB_B; ++b) acc[b] = bias1;
        #pragma unroll
        for (int kc = 0; kc < 32; ++kc) {
          WCVT(wih_r[kc], wa, wb)
          #pragma unroll
          for (int b = 0; b < NB_B; ++b) {
            float4 hv = *(const float4*)&hbuf[b * 320 + 64 + kc * 4];
            acc[b] = fmaf(wa.x, hv.x, fmaf(wa.y, hv.y,
                     fmaf(wb.x, hv.z, fmaf(wb.y, hv.w, acc[b]))));
          }
        }
        #pragma unroll
        for (int kc = 0; kc < 32; ++kc) {
          WCVT(whh_r[kc], wa, wb)
          #pragma unroll
          for (int b = 0; b < NB_B; ++b) {
            float4 hv = *(const float4*)&hbuf[b * 320 + 192 + kc * 4];
            acc[b] = fmaf(wa.x, hv.x, fmaf(wa.y, hv.y,
                     fmaf(wb.x, hv.z, fmaf(wb.y, hv.w, acc[b]))));
          }
        }
        gacc[0 * 512 + r] = acc[0];
        gacc[1 * 512 + r] = acc[1];
        gacc[2 * 512 + r] = acc[2];
        gacc[3 * 512 + r] = acc[3];
      }
      __syncthreads();                 // gacc ready; hbuf reads done; rv arrived

      {  // update -> h1[s]; stash at end; stage h0[s+1] from register
        const float* gb = &gacc[bp * 512];
        float gi = gb[u], gf = gb[128 + u], gg = gb[256 + u], go = gb[384 + u];
        float cc = sig1(gf) * c1 + sig1(gi) * tanh1(gg);
        c1 = cc;
        float hvv = sig1(go) * tanh1(cc);
        hbuf[bp * 320 + 192 + u] = hvv;
        if (s == SEQ - 1)
          out[(size_t)(96 + p) * SLICE + 1024 + bp * 128 + u] = hvv;
      }
      if (pf) hbuf[bp * 320 + 64 + u] = rv;
      __syncthreads();                 // LDS consistent for next iter
      if (tid == 0) astoreu(flagC, (unsigned)(s + 2));   // slots <= s+1 consumed
      if (++sl == 3) sl = 0;
    }
  }
}

// base[b][m] = b1[m] + W1[m,0:128].hL[b] + W1[m,128:256].hR[b] -> out[b*SLICE + m]
extern "C" __global__ void __launch_bounds__(128)
mlp2_pre(const float* __restrict__ W1, const float* __restrict__ b1, float* out) {
  __shared__ float inpS[256];
  const int b = blockIdx.x, tid = threadIdx.x;
  inpS[tid]       = out[(size_t)(96  + (b >> 2)) * SLICE + 1024 + (b & 3) * 128 + tid];
  inpS[128 + tid] = out[(size_t)(160 + (b >> 2)) * SLICE + 1024 + (b & 3) * 128 + tid];
  __syncthreads();
  const float* wr = W1 + (size_t)tid * 257;
  float s = b1[tid];
  #pragma unroll 4
  for (int k = 0; k < 256; ++k) s = fmaf(wr[k], inpS[k], s);
  out[(size_t)b * SLICE + tid] = s;
}

// out[b][t][o] = b2[o] + sum_m W2[o][m] * relu(base[b][m] + W1[m][256]*T[b][t])
extern "C" __global__ void __launch_bounds__(256)
mlp2_k(const float* __restrict__ T, const float* __restrict__ W1,
       const float* __restrict__ b2, const float* __restrict__ W2, float* out) {
  __shared__ float baseS[128], w1l[128], w2S[384];
  const int b = blockIdx.x, tid = threadIdx.x;
  if (tid < 128) {
    baseS[tid] = out[(size_t)b * SLICE + tid];   // read own slice BEFORE any write
    w1l[tid]   = W1[(size_t)tid * 257 + 256];
  }
  w2S[tid] = W2[tid];                            // 256 threads fill all 384
  if (tid < 128) w2S[256 + tid] = W2[256 + tid];
  __syncthreads();
  float x[4];
  #pragma unroll
  for (int q = 0; q < 4; ++q) x[q] = T[(size_t)b * TLEN + tid + q * 256];
  float a0[4], a1[4], a2[4];
  #pragma unroll
  for (int q = 0; q < 4; ++q) { a0[q] = b2[0]; a1[q] = b2[1]; a2[q] = b2[2]; }
  for (int mm = 0; mm < 128; ++mm) {
    float bm = baseS[mm], wl = w1l[mm];
    float w20 = w2S[mm], w21 = w2S[128 + mm], w22 = w2S[256 + mm];
    #pragma unroll
    for (int q = 0; q < 4; ++q) {
      float hv = fmaxf(fmaf(wl, x[q], bm), 0.0f);
      a0[q] = fmaf(w20, hv, a0[q]);
      a1[q] = fmaf(w21, hv, a1[q]);
      a2[q] = fmaf(w22, hv, a2[q]);
    }
  }
  #pragma unroll
  for (int q = 0; q < 4; ++q) {
    float* o = out + ((size_t)b * TLEN + tid + q * 256) * 3;
    o[0] = a0[q]; o[1] = a1[q]; o[2] = a2[q];
  }
}

extern "C" void kernel_launch(void* const* d_in, const int* in_sizes, int n_in,
                              void* d_out, int out_size, void* d_ws, size_t ws_size,
                              hipStream_t stream) {
  (void)in_sizes; (void)n_in; (void)out_size; (void)d_ws; (void)ws_size;
  const float* X1   = (const float*)d_in[0];
  const float* X2   = (const float*)d_in[1];
  const float* T    = (const float*)d_in[2];
  const float* W1m  = (const float*)d_in[3];
  const float* b1m  = (const float*)d_in[4];
  const float* Wih0 = (const float*)d_in[5];
  const float* Whh0 = (const float*)d_in[6];
  const float* bih0 = (const float*)d_in[7];
  const float* bhh0 = (const float*)d_in[8];
  const float* Wih1 = (const float*)d_in[9];
  const float* Whh1 = (const float*)d_in[10];
  const float* bih1 = (const float*)d_in[11];
  const float* bhh1 = (const float*)d_in[12];
  const float* W1p  = (const float*)d_in[13];
  const float* b1p  = (const float*)d_in[14];
  const float* W2p  = (const float*)d_in[15];
  const float* b2p  = (const float*)d_in[16];

  float* out = (float*)d_out;

  // flags must start at 0 every call
  hipMemsetAsync((char*)d_out + (size_t)FLAGF * 4, 0, 65536, stream);

  prep_t<<<dim3(896), dim3(256), 0, stream>>>(Wih0, Whh0, Wih1, Whh1, (__half*)out);
  lstm_pair<<<dim3(256), dim3(NTHR), 0, stream>>>(X1, X2, W1m, b1m,
                                                  bih0, bhh0, bih1, bhh1, out, out);
  mlp2_pre<<<dim3(256), dim3(128), 0, stream>>>(W1p, b1p, out);
  mlp2_k<<<dim3(256), dim3(256), 0, stream>>>(T, W1p, b2p, W2p, out);
}

// Round 18
// 8636.069 us; speedup vs baseline: 1.2150x; 1.2150x over previous
//
#include <hip/hip_runtime.h>
#include <hip/hip_fp16.h>

#define SEQ   1024
#define TLEN  1024
#define NB_B  2          // batches per pair (2 blocks/CU for latency overlap)
#define NPAIR 256
#define NTHR  512
#define SLICE 3072

// d_out float map (786,432 floats):
//  [0,114688)       fp16 transposed weights (229376 halves, prep_t)
//  [114688,180224)  h0 ring slot0 [256 pairs][256]
//  [180224,245760)  h0 ring slot1
//  [688128,753664)  h0 ring slot2          (stash ends 686592; flags start 753664)
//  [753664,770048)  flags: flag0[p] @ +p*32, flagC[p] @ +8192+p*32 (memset 0)
//  slices 96..223 @ offset [1024,1536): final-h stash = floats [295936,686592)
#define WT0IH 0
#define WT0HH 32768
#define WT1IH 98304
#define WT1HH 163840
#define WTOT  229376
#define RINGA 114688
#define RINGB 180224
#define RINGC 688128
#define FLAGF 753664

__device__ __forceinline__ float sig1(float x)  { return 1.0f / (1.0f + __expf(-x)); }
__device__ __forceinline__ float tanh1(float x) { return 1.0f - 2.0f / (__expf(2.0f * x) + 1.0f); }

__device__ __forceinline__ void astoref(float* pp, float v) {
  __hip_atomic_store(pp, v, __ATOMIC_RELAXED, __HIP_MEMORY_SCOPE_AGENT);
}
__device__ __forceinline__ float aloadf(const float* pp) {
  return __hip_atomic_load(pp, __ATOMIC_RELAXED, __HIP_MEMORY_SCOPE_AGENT);
}
__device__ __forceinline__ void astoreu(unsigned* pp, unsigned v) {
  __hip_atomic_store(pp, v, __ATOMIC_RELAXED, __HIP_MEMORY_SCOPE_AGENT);
}
__device__ __forceinline__ unsigned aloadu(const unsigned* pp) {
  return __hip_atomic_load(pp, __ATOMIC_RELAXED, __HIP_MEMORY_SCOPE_AGENT);
}
__device__ __forceinline__ int rbase(int sl) {   // ring slot -> d_out float offset
  return (sl == 2) ? RINGC : (RINGA + sl * 65536);
}

// One-time weight transpose+cast: [row][k] fp32 -> fp16 [k>>2][row][k&3] in d_out
extern "C" __global__ void __launch_bounds__(256)
prep_t(const float* __restrict__ Wih0, const float* __restrict__ Whh0,
       const float* __restrict__ Wih1, const float* __restrict__ Whh1,
       __half* __restrict__ wt16) {
  const int idx = blockIdx.x * 256 + threadIdx.x;
  if (idx >= WTOT) return;
  float v; int r, k, base;
  if (idx < 32768)      { r = idx >> 6;  k = idx & 63;                  v = Wih0[idx]; base = WT0IH; }
  else if (idx < 98304) { int j = idx - 32768;  r = j >> 7; k = j & 127; v = Whh0[j];  base = WT0HH; }
  else if (idx < 163840){ int j = idx - 98304;  r = j >> 7; k = j & 127; v = Wih1[j];  base = WT1IH; }
  else                  { int j = idx - 163840; r = j >> 7; k = j & 127; v = Whh1[j];  base = WT1HH; }
  wt16[base + (((k >> 2) * 512 + r) << 2) + (k & 3)] = __float2half(v);
}

// fp16 weight quad -> two float2
#define WCVT(wp, wa, wb)                                                    \
  float2 wa = __half22float2(*reinterpret_cast<const __half2*>(&(wp).x));   \
  float2 wb = __half22float2(*reinterpret_cast<const __half2*>(&(wp).y));

// Paired pipeline at 2-batch granularity: 256 pairs, 512 blocks, 2 blocks/CU.
// PLAIN launch (r17's cooperative launch of 512 blocks was silently rejected —
// all prior coop successes were exactly 256 blocks). Co-residency by capacity:
// 512 blocks x 8 waves = 4096 waves << 8192-wave chip capacity at 64 VGPR /
// 6.7 KB LDS, and nothing else shares the device. Even bid = layer0 of pair
// bid>>1; odd bid = layer1 ~2 steps behind. Ring depth 3, reg-prefetched h0,
// 2 syncs/step, fp16 weights streamed from L2 (r15-proven loops, NB_B=2).
extern "C" __global__ void __launch_bounds__(NTHR, 4)
lstm_pair(const float* __restrict__ X1, const float* __restrict__ X2,
          const float* __restrict__ W1m, const float* __restrict__ b1m,
          const float* __restrict__ bih0, const float* __restrict__ bhh0,
          const float* __restrict__ bih1, const float* __restrict__ bhh1,
          const float* wt, float* out) {
  __shared__ float hbuf[NB_B * 320];   // per batch: feat[64] | h0[128] | h1[128]
  __shared__ float gacc[NB_B * 512];   // [batch][gate-row]  (conflict-free)

  const int tid = threadIdx.x;
  const int bid = blockIdx.x;
  const bool L1role = (bid & 1) != 0;
  const int p  = bid >> 1;
  const int r  = tid;                  // gate row 0..511
  const int u  = tid & 127;            // hidden unit
  const int bq = tid >> 7;             // batch slot 0..3 (active if < NB_B)

  const __half* wt16 = (const __half*)wt;
  unsigned* flag0 = (unsigned*)(out + FLAGF) + p * 32;          // L0 progress
  unsigned* flagC = (unsigned*)(out + FLAGF) + 8192 + p * 32;   // L1 consumed

  for (int i = tid; i < NB_B * 320; i += NTHR) hbuf[i] = 0.0f;
  __syncthreads();

  if (!L1role) {
    // ---------------- layer-0 producer ----------------
    const int m  = tid & 63;           // mlp1 unit
    const int bf = tid >> 6;           // mlp1 batch slot (active if < NB_B)
    float w1r[5]; float b1r = 0.0f;
    const float* xptr = X1;
    if (bf < NB_B) {
      #pragma unroll
      for (int i = 0; i < 5; ++i) w1r[i] = W1m[m * 5 + i];
      b1r = b1m[m];
      const int ebx = p * NB_B + bf;
      xptr = (ebx < 256) ? (X1 + (size_t)ebx * SEQ * 5)
                         : (X2 + (size_t)(ebx - 256) * SEQ * 5);
    }
    const float bias0 = bih0[r] + bhh0[r];
    const uint2* wih0 = (const uint2*)(wt16 + WT0IH) + r;  // [kc][512] half-quads
    const uint2* whh0 = (const uint2*)(wt16 + WT0HH) + r;

    // prologue: feat[0]
    if (bf < NB_B) {
      float s = b1r;
      #pragma unroll
      for (int i = 0; i < 5; ++i) s = fmaf(w1r[i], xptr[i], s);
      hbuf[bf * 320 + m] = fmaxf(s, 0.0f);
    }
    __syncthreads();

    float c0 = 0.0f;
    int sl = 0;                        // slot(t)
    unsigned fcs = 0;                  // cached flagC (monotonic)
    for (int t = 0; t < SEQ; ++t) {
      // slot-reuse guard: L1 must have consumed h0[t-3] (tid0; post-gates sync
      // orders every thread's ring store after this poll)
      if (tid == 0 && t >= 3) {
        const unsigned tgt = (unsigned)(t - 2);
        while (fcs < tgt) {
          fcs = aloadu(flagC);
          if (fcs < tgt) __builtin_amdgcn_s_sleep(2);
        }
      }

      {  // layer0 gate rows: Wih0.feat[t] + Whh0.h0[t-1]   (r15-proven loop)
        float acc[NB_B];
        #pragma unroll
        for (int b = 0; b < NB_B; ++b) acc[b] = bias0;
        #pragma unroll 4
        for (int kc = 0; kc < 16; ++kc) {
          uint2 wp = wih0[kc * 512];
          WCVT(wp, wa, wb)
          #pragma unroll
          for (int b = 0; b < NB_B; ++b) {
            float4 hv = *(const float4*)&hbuf[b * 320 + kc * 4];
            acc[b] = fmaf(wa.x, hv.x, fmaf(wa.y, hv.y,
                     fmaf(wb.x, hv.z, fmaf(wb.y, hv.w, acc[b]))));
          }
        }
        #pragma unroll 4
        for (int kc = 0; kc < 32; ++kc) {
          uint2 wp = whh0[kc * 512];
          WCVT(wp, wa, wb)
          #pragma unroll
          for (int b = 0; b < NB_B; ++b) {
            float4 hv = *(const float4*)&hbuf[b * 320 + 64 + kc * 4];
            acc[b] = fmaf(wa.x, hv.x, fmaf(wa.y, hv.y,
                     fmaf(wb.x, hv.z, fmaf(wb.y, hv.w, acc[b]))));
          }
        }
        #pragma unroll
        for (int b = 0; b < NB_B; ++b) gacc[b * 512 + r] = acc[b];
      }
      __syncthreads();                 // gacc ready; hbuf reads done; poll done

      // update -> h0[t] (LDS + ring publish) ; feat[t+1]
      if (bq < NB_B) {
        const float* gb = &gacc[bq * 512];
        float gi = gb[u], gf = gb[128 + u], gg = gb[256 + u], go = gb[384 + u];
        float cc = sig1(gf) * c0 + sig1(gi) * tanh1(gg);
        c0 = cc;
        float hv = sig1(go) * tanh1(cc);
        hbuf[bq * 320 + 64 + u] = hv;
        astoref(out + rbase(sl) + p * 256 + tid, hv);   // tid = bq*128+u
      }
      if (bf < NB_B && t + 1 < SEQ) {
        const float* x = xptr + (size_t)(t + 1) * 5;
        float s = b1r;
        s = fmaf(w1r[0], x[0], s); s = fmaf(w1r[1], x[1], s);
        s = fmaf(w1r[2], x[2], s); s = fmaf(w1r[3], x[3], s);
        s = fmaf(w1r[4], x[4], s);
        hbuf[bf * 320 + m] = fmaxf(s, 0.0f);
      }
      __syncthreads();                 // ring stores drained (vmcnt0) + LDS ready
      if (tid == 0) astoreu(flag0, (unsigned)(t + 1));
      if (++sl == 3) sl = 0;
    }
  } else {
    // ---------------- layer-1 consumer ----------------
    const float bias1 = bih1[r] + bhh1[r];
    const uint2* wih1 = (const uint2*)(wt16 + WT1IH) + r;
    const uint2* whh1 = (const uint2*)(wt16 + WT1HH) + r;

    // prologue: stage h0[0]
    {
      unsigned f0 = aloadu(flag0);
      while (f0 < 1u) { __builtin_amdgcn_s_sleep(2); f0 = aloadu(flag0); }
      if (bq < NB_B) hbuf[bq * 320 + 64 + u] = aloadf(out + RINGA + p * 256 + tid);
    }
    __syncthreads();

    float c1 = 0.0f;
    int sl = 1;                        // slot(s+1)
    unsigned f0s = 0;                  // cached flag0 (monotonic)
    for (int s = 0; s < SEQ; ++s) {
      // prefetch h0[s+1] into a register; latency hidden under gates
      float rv = 0.0f;
      const bool pf = (s + 1 < SEQ);
      if (pf) {
        const unsigned tgt = (unsigned)(s + 2);
        while (f0s < tgt) {
          f0s = aloadu(flag0);
          if (f0s < tgt) __builtin_amdgcn_s_sleep(2);
        }
        if (bq < NB_B) rv = aloadf(out + rbase(sl) + p * 256 + tid);
      }

      {  // layer1 gate rows: Wih1.h0[s] + Whh1.h1[s-1]   (r15-proven loop)
        float acc[NB_B];
        #pragma unroll
        for (int b = 0; b < NB_B; ++b) acc[b] = bias1;
        #pragma unroll 4
        for (int kc = 0; kc < 32; ++kc) {
          uint2 wp = wih1[kc * 512];
          WCVT(wp, wa, wb)
          #pragma unroll
          for (int b = 0; b < NB_B; ++b) {
            float4 hv = *(const float4*)&hbuf[b * 320 + 64 + kc * 4];
            acc[b] = fmaf(wa.x, hv.x, fmaf(wa.y, hv.y,
                     fmaf(wb.x, hv.z, fmaf(wb.y, hv.w, acc[b]))));
          }
        }
        #pragma unroll 4
        for (int kc = 0; kc < 32; ++kc) {
          uint2 wp = whh1[kc * 512];
          WCVT(wp, wa, wb)
          #pragma unroll
          for (int b = 0; b < NB_B; ++b) {
            float4 hv = *(const float4*)&hbuf[b * 320 + 192 + kc * 4];
            acc[b] = fmaf(wa.x, hv.x, fmaf(wa.y, hv.y,
                     fmaf(wb.x, hv.z, fmaf(wb.y, hv.w, acc[b]))));
          }
        }
        #pragma unroll
        for (int b = 0; b < NB_B; ++b) gacc[b * 512 + r] = acc[b];
      }
      __syncthreads();                 // gacc ready; hbuf reads done; rv arrived

      if (bq < NB_B) {  // update -> h1[s]; stash at end; stage h0[s+1] from reg
        const float* gb = &gacc[bq * 512];
        float gi = gb[u], gf = gb[128 + u], gg = gb[256 + u], go = gb[384 + u];
        float cc = sig1(gf) * c1 + sig1(gi) * tanh1(gg);
        c1 = cc;
        float hvv = sig1(go) * tanh1(cc);
        hbuf[bq * 320 + 192 + u] = hvv;
        if (s == SEQ - 1) {
          const int v = p * NB_B + bq;   // merged batch 0..511
          out[(size_t)(96 + (v >> 2)) * SLICE + 1024 + (v & 3) * 128 + u] = hvv;
        }
        if (pf) hbuf[bq * 320 + 64 + u] = rv;
      }
      __syncthreads();                 // LDS consistent for next iter
      if (tid == 0) astoreu(flagC, (unsigned)(s + 2));   // slots <= s+1 consumed
      if (++sl == 3) sl = 0;
    }
  }
}

// base[b][m] = b1[m] + W1[m,0:128].hL[b] + W1[m,128:256].hR[b] -> out[b*SLICE + m]
extern "C" __global__ void __launch_bounds__(128)
mlp2_pre(const float* __restrict__ W1, const float* __restrict__ b1, float* out) {
  __shared__ float inpS[256];
  const int b = blockIdx.x, tid = threadIdx.x;
  inpS[tid]       = out[(size_t)(96  + (b >> 2)) * SLICE + 1024 + (b & 3) * 128 + tid];
  inpS[128 + tid] = out[(size_t)(160 + (b >> 2)) * SLICE + 1024 + (b & 3) * 128 + tid];
  __syncthreads();
  const float* wr = W1 + (size_t)tid * 257;
  float s = b1[tid];
  #pragma unroll 4
  for (int k = 0; k < 256; ++k) s = fmaf(wr[k], inpS[k], s);
  out[(size_t)b * SLICE + tid] = s;
}

// out[b][t][o] = b2[o] + sum_m W2[o][m] * relu(base[b][m] + W1[m][256]*T[b][t])
extern "C" __global__ void __launch_bounds__(256)
mlp2_k(const float* __restrict__ T, const float* __restrict__ W1,
       const float* __restrict__ b2, const float* __restrict__ W2, float* out) {
  __shared__ float baseS[128], w1l[128], w2S[384];
  const int b = blockIdx.x, tid = threadIdx.x;
  if (tid < 128) {
    baseS[tid] = out[(size_t)b * SLICE + tid];   // read own slice BEFORE any write
    w1l[tid]   = W1[(size_t)tid * 257 + 256];
  }
  w2S[tid] = W2[tid];                            // 256 threads fill all 384
  if (tid < 128) w2S[256 + tid] = W2[256 + tid];
  __syncthreads();
  float x[4];
  #pragma unroll
  for (int q = 0; q < 4; ++q) x[q] = T[(size_t)b * TLEN + tid + q * 256];
  float a0[4], a1[4], a2[4];
  #pragma unroll
  for (int q = 0; q < 4; ++q) { a0[q] = b2[0]; a1[q] = b2[1]; a2[q] = b2[2]; }
  for (int mm = 0; mm < 128; ++mm) {
    float bm = baseS[mm], wl = w1l[mm];
    float w20 = w2S[mm], w21 = w2S[128 + mm], w22 = w2S[256 + mm];
    #pragma unroll
    for (int q = 0; q < 4; ++q) {
      float hv = fmaxf(fmaf(wl, x[q], bm), 0.0f);
      a0[q] = fmaf(w20, hv, a0[q]);
      a1[q] = fmaf(w21, hv, a1[q]);
      a2[q] = fmaf(w22, hv, a2[q]);
    }
  }
  #pragma unroll
  for (int q = 0; q < 4; ++q) {
    float* o = out + ((size_t)b * TLEN + tid + q * 256) * 3;
    o[0] = a0[q]; o[1] = a1[q]; o[2] = a2[q];
  }
}

extern "C" void kernel_launch(void* const* d_in, const int* in_sizes, int n_in,
                              void* d_out, int out_size, void* d_ws, size_t ws_size,
                              hipStream_t stream) {
  (void)in_sizes; (void)n_in; (void)out_size; (void)d_ws; (void)ws_size;
  const float* X1   = (const float*)d_in[0];
  const float* X2   = (const float*)d_in[1];
  const float* T    = (const float*)d_in[2];
  const float* W1m  = (const float*)d_in[3];
  const float* b1m  = (const float*)d_in[4];
  const float* Wih0 = (const float*)d_in[5];
  const float* Whh0 = (const float*)d_in[6];
  const float* bih0 = (const float*)d_in[7];
  const float* bhh0 = (const float*)d_in[8];
  const float* Wih1 = (const float*)d_in[9];
  const float* Whh1 = (const float*)d_in[10];
  const float* bih1 = (const float*)d_in[11];
  const float* bhh1 = (const float*)d_in[12];
  const float* W1p  = (const float*)d_in[13];
  const float* b1p  = (const float*)d_in[14];
  const float* W2p  = (const float*)d_in[15];
  const float* b2p  = (const float*)d_in[16];

  float* out = (float*)d_out;

  // flags must start at 0 every call
  hipMemsetAsync((char*)d_out + (size_t)FLAGF * 4, 0, 65536, stream);

  prep_t<<<dim3(896), dim3(256), 0, stream>>>(Wih0, Whh0, Wih1, Whh1, (__half*)out);

  lstm_pair<<<dim3(2 * NPAIR), dim3(NTHR), 0, stream>>>(X1, X2, W1m, b1m,
                                                        bih0, bhh0, bih1, bhh1,
                                                        out, out);

  mlp2_pre<<<dim3(256), dim3(128), 0, stream>>>(W1p, b1p, out);
  mlp2_k<<<dim3(256), dim3(256), 0, stream>>>(T, W1p, b2p, W2p, out);
}

// Round 19
// 4711.565 us; speedup vs baseline: 2.2271x; 1.8330x over previous
//
#include <hip/hip_runtime.h>
#include <hip/hip_fp16.h>

#define SEQ   1024
#define TLEN  1024
#define NB_B  4
#define NPAIR 128
#define NTHR  512
#define SLICE 3072

// d_out float map (786,432 floats):
//  [0,114688)       fp16 transposed weights (229376 halves, prep_t)
//  [114688,180224)  h0 ring slot0 [128 pairs][512]
//  [180224,245760)  h0 ring slot1
//  [688128,753664)  h0 ring slot2          (stash ends 686592; flags start 753664)
//  [753664,770048)  flags: flag0[p] @ +p*64, flagC[p] @ +8192+p*64 (memset 0)
//  slices 96..223 @ offset [1024,1536): final-h stash = floats [295936,686592)
// Weight HALF-index offsets (within half-array at d_out base):
#define WT0IH 0
#define WT0HH 32768
#define WT1IH 98304
#define WT1HH 163840
#define WTOT  229376
#define RINGA 114688
#define RINGB 180224
#define RINGC 688128
#define FLAGF 753664

__device__ __forceinline__ float sig1(float x)  { return 1.0f / (1.0f + __expf(-x)); }
__device__ __forceinline__ float tanh1(float x) { return 1.0f - 2.0f / (__expf(2.0f * x) + 1.0f); }

__device__ __forceinline__ void astoref(float* pp, float v) {
  __hip_atomic_store(pp, v, __ATOMIC_RELAXED, __HIP_MEMORY_SCOPE_AGENT);
}
__device__ __forceinline__ float aloadf(const float* pp) {
  return __hip_atomic_load(pp, __ATOMIC_RELAXED, __HIP_MEMORY_SCOPE_AGENT);
}
__device__ __forceinline__ void astoreu(unsigned* pp, unsigned v) {
  __hip_atomic_store(pp, v, __ATOMIC_RELAXED, __HIP_MEMORY_SCOPE_AGENT);
}
__device__ __forceinline__ unsigned aloadu(const unsigned* pp) {
  return __hip_atomic_load(pp, __ATOMIC_RELAXED, __HIP_MEMORY_SCOPE_AGENT);
}
__device__ __forceinline__ int rbase(int sl) {   // ring slot -> d_out float offset
  return (sl == 2) ? RINGC : (RINGA + sl * 65536);
}

// fp16 pair-dot with fp32 accumulate: acc += a.h0*b.h0 + a.h1*b.h1
typedef _Float16 h2v __attribute__((ext_vector_type(2)));
__device__ __forceinline__ float dot2h(unsigned a, unsigned b, float c) {
#if __has_builtin(__builtin_amdgcn_fdot2)
  return __builtin_amdgcn_fdot2(__builtin_bit_cast(h2v, a),
                                __builtin_bit_cast(h2v, b), c, false);
#else
  float2 fa = __half22float2(__builtin_bit_cast(__half2, a));
  float2 fb = __half22float2(__builtin_bit_cast(__half2, b));
  return fmaf(fa.x, fb.x, fmaf(fa.y, fb.y, c));
#endif
}

// One-time weight transpose+cast: [row][k] fp32 -> fp16 [k>>2][row][k&3] in d_out
extern "C" __global__ void __launch_bounds__(256)
prep_t(const float* __restrict__ Wih0, const float* __restrict__ Whh0,
       const float* __restrict__ Wih1, const float* __restrict__ Whh1,
       __half* __restrict__ wt16) {
  const int idx = blockIdx.x * 256 + threadIdx.x;
  if (idx >= WTOT) return;
  float v; int r, k, base;
  if (idx < 32768)      { r = idx >> 6;  k = idx & 63;                  v = Wih0[idx]; base = WT0IH; }
  else if (idx < 98304) { int j = idx - 32768;  r = j >> 7; k = j & 127; v = Whh0[j];  base = WT0HH; }
  else if (idx < 163840){ int j = idx - 98304;  r = j >> 7; k = j & 127; v = Wih1[j];  base = WT1IH; }
  else                  { int j = idx - 163840; r = j >> 7; k = j & 127; v = Whh1[j];  base = WT1HH; }
  wt16[base + (((k >> 2) * 512 + r) << 2) + (k & 3)] = __float2half(v);
}

// Paired pipeline (r15-proven protocol: 128 pairs, 256 blocks, ring depth 3,
// reg-prefetched h0, 2 syncs/step). NEW: h tiles stored fp16 in LDS (one
// ds_read_b128 = 8 k-values -> LDS instr halved) and gates computed with
// v_dot2_f32_f16 (2 MAC/instr, fp32 accum, no cvt). State stays fp32.
extern "C" __global__ void __launch_bounds__(NTHR)
lstm_pair(const float* __restrict__ X1, const float* __restrict__ X2,
          const float* __restrict__ W1m, const float* __restrict__ b1m,
          const float* __restrict__ bih0, const float* __restrict__ bhh0,
          const float* __restrict__ bih1, const float* __restrict__ bhh1,
          const float* wt, float* out) {
  __shared__ __align__(16) __half hbuf[NB_B * 320];  // per batch: feat[64]|h0[128]|h1[128]
  __shared__ float gacc[NB_B * 512];                 // [batch][gate-row] (conflict-free)

  const int tid = threadIdx.x;
  const int bid = blockIdx.x;
  const bool L1role = bid >= NPAIR;
  const int p  = L1role ? bid - NPAIR : bid;
  const int r  = tid;                  // gate row 0..511
  const int u  = tid & 127;            // hidden unit
  const int bq = tid >> 7;             // batch slot 0..3

  const __half* wt16 = (const __half*)wt;
  unsigned* flag0 = (unsigned*)(out + FLAGF) + p * 64;          // L0 progress
  unsigned* flagC = (unsigned*)(out + FLAGF) + 8192 + p * 64;   // L1 consumed

  for (int i = tid; i < NB_B * 320; i += NTHR) hbuf[i] = __float2half(0.0f);
  __syncthreads();

  if (!L1role) {
    // ---------------- layer-0 producer ----------------
    const int m  = tid & 63;           // mlp1 unit
    const int bf = tid >> 6;           // mlp1 batch slot (active if < NB_B)
    float w1r[5]; float b1r = 0.0f;
    const float* xptr = X1;
    if (bf < NB_B) {
      #pragma unroll
      for (int i = 0; i < 5; ++i) w1r[i] = W1m[m * 5 + i];
      b1r = b1m[m];
      const int ebx = p * NB_B + bf;
      xptr = (ebx < 256) ? (X1 + (size_t)ebx * SEQ * 5)
                         : (X2 + (size_t)(ebx - 256) * SEQ * 5);
    }
    const float bias0 = bih0[r] + bhh0[r];
    // seamless quad stream: Wih0 quads 0..15, Whh0 quads 16..47 (contiguous)
    const uint2* w0s = (const uint2*)wt16 + r;

    // prologue: feat[0]
    if (bf < NB_B) {
      float s = b1r;
      #pragma unroll
      for (int i = 0; i < 5; ++i) s = fmaf(w1r[i], xptr[i], s);
      hbuf[bf * 320 + m] = __float2half(fmaxf(s, 0.0f));
    }
    __syncthreads();

    float c0 = 0.0f;
    int sl = 0;                        // slot(t)
    unsigned fcs = 0;                  // cached flagC (monotonic)
    for (int t = 0; t < SEQ; ++t) {
      if (tid == 0 && t >= 3) {        // L1 must have consumed h0[t-3]
        const unsigned tgt = (unsigned)(t - 2);
        while (fcs < tgt) {
          fcs = aloadu(flagC);
          if (fcs < tgt) __builtin_amdgcn_s_sleep(2);
        }
      }

      {  // gates: 24 8-k chunks over [feat|h0] (fp16 LDS, dot2)
        float acc[NB_B];
        #pragma unroll
        for (int b = 0; b < NB_B; ++b) acc[b] = bias0;
        #pragma unroll 2
        for (int c = 0; c < 24; ++c) {
          uint2 wq0 = w0s[(2 * c)     * 512];
          uint2 wq1 = w0s[(2 * c + 1) * 512];
          #pragma unroll
          for (int b = 0; b < NB_B; ++b) {
            uint4 hv = *(const uint4*)&hbuf[b * 320 + c * 8];
            acc[b] = dot2h(wq0.x, hv.x, acc[b]);
            acc[b] = dot2h(wq0.y, hv.y, acc[b]);
            acc[b] = dot2h(wq1.x, hv.z, acc[b]);
            acc[b] = dot2h(wq1.y, hv.w, acc[b]);
          }
        }
        #pragma unroll
        for (int b = 0; b < NB_B; ++b) gacc[b * 512 + r] = acc[b];
      }
      __syncthreads();                 // gacc ready; hbuf reads done; poll done

      // update -> h0[t] (LDS fp16 + fp32 ring publish) ; feat[t+1]
      {
        const float* gb = &gacc[bq * 512];
        float gi = gb[u], gf = gb[128 + u], gg = gb[256 + u], go = gb[384 + u];
        float cc = sig1(gf) * c0 + sig1(gi) * tanh1(gg);
        c0 = cc;
        float hval = sig1(go) * tanh1(cc);
        hbuf[bq * 320 + 64 + u] = __float2half(hval);
        astoref(out + rbase(sl) + p * 512 + tid, hval);
      }
      if (bf < NB_B && t + 1 < SEQ) {
        const float* x = xptr + (size_t)(t + 1) * 5;
        float s = b1r;
        s = fmaf(w1r[0], x[0], s); s = fmaf(w1r[1], x[1], s);
        s = fmaf(w1r[2], x[2], s); s = fmaf(w1r[3], x[3], s);
        s = fmaf(w1r[4], x[4], s);
        hbuf[bf * 320 + m] = __float2half(fmaxf(s, 0.0f));
      }
      __syncthreads();                 // ring stores drained (vmcnt0) + LDS ready
      if (tid == 0) astoreu(flag0, (unsigned)(t + 1));
      if (++sl == 3) sl = 0;
    }
  } else {
    // ---------------- layer-1 consumer ----------------
    const float bias1 = bih1[r] + bhh1[r];
    // seamless quad stream: Wih1 quads 0..31, Whh1 quads 32..63 (contiguous)
    const uint2* w1s = (const uint2*)(wt16 + WT1IH) + r;

    // prologue: stage h0[0]
    {
      unsigned f0 = aloadu(flag0);
      while (f0 < 1u) { __builtin_amdgcn_s_sleep(2); f0 = aloadu(flag0); }
      hbuf[bq * 320 + 64 + u] = __float2half(aloadf(out + RINGA + p * 512 + tid));
    }
    __syncthreads();

    float c1 = 0.0f;
    int sl = 1;                        // slot(s+1)
    unsigned f0s = 0;                  // cached flag0 (monotonic)
    for (int s = 0; s < SEQ; ++s) {
      // prefetch h0[s+1] into a register; latency hidden under gates
      float rv = 0.0f;
      const bool pf = (s + 1 < SEQ);
      if (pf) {
        const unsigned tgt = (unsigned)(s + 2);
        while (f0s < tgt) {
          f0s = aloadu(flag0);
          if (f0s < tgt) __builtin_amdgcn_s_sleep(2);
        }
        rv = aloadf(out + rbase(sl) + p * 512 + tid);
      }

      {  // gates: 32 8-k chunks over [h0|h1] (fp16 LDS, dot2)
        float acc[NB_B];
        #pragma unroll
        for (int b = 0; b < NB_B; ++b) acc[b] = bias1;
        #pragma unroll 2
        for (int c = 0; c < 32; ++c) {
          uint2 wq0 = w1s[(2 * c)     * 512];
          uint2 wq1 = w1s[(2 * c + 1) * 512];
          #pragma unroll
          for (int b = 0; b < NB_B; ++b) {
            uint4 hv = *(const uint4*)&hbuf[b * 320 + 64 + c * 8];
            acc[b] = dot2h(wq0.x, hv.x, acc[b]);
            acc[b] = dot2h(wq0.y, hv.y, acc[b]);
            acc[b] = dot2h(wq1.x, hv.z, acc[b]);
            acc[b] = dot2h(wq1.y, hv.w, acc[b]);
          }
        }
        #pragma unroll
        for (int b = 0; b < NB_B; ++b) gacc[b * 512 + r] = acc[b];
      }
      __syncthreads();                 // gacc ready; hbuf reads done; rv arrived

      {  // update -> h1[s]; stash at end; stage h0[s+1] from register
        const float* gb = &gacc[bq * 512];
        float gi = gb[u], gf = gb[128 + u], gg = gb[256 + u], go = gb[384 + u];
        float cc = sig1(gf) * c1 + sig1(gi) * tanh1(gg);
        c1 = cc;
        float hvv = sig1(go) * tanh1(cc);
        hbuf[bq * 320 + 192 + u] = __float2half(hvv);
        if (s == SEQ - 1)
          out[(size_t)(96 + p) * SLICE + 1024 + bq * 128 + u] = hvv;
      }
      if (pf) hbuf[bq * 320 + 64 + u] = __float2half(rv);
      __syncthreads();                 // LDS consistent for next iter
      if (tid == 0) astoreu(flagC, (unsigned)(s + 2));   // slots <= s+1 consumed
      if (++sl == 3) sl = 0;
    }
  }
}

// base[b][m] = b1[m] + W1[m,0:128].hL[b] + W1[m,128:256].hR[b] -> out[b*SLICE + m]
extern "C" __global__ void __launch_bounds__(128)
mlp2_pre(const float* __restrict__ W1, const float* __restrict__ b1, float* out) {
  __shared__ float inpS[256];
  const int b = blockIdx.x, tid = threadIdx.x;
  inpS[tid]       = out[(size_t)(96  + (b >> 2)) * SLICE + 1024 + (b & 3) * 128 + tid];
  inpS[128 + tid] = out[(size_t)(160 + (b >> 2)) * SLICE + 1024 + (b & 3) * 128 + tid];
  __syncthreads();
  const float* wr = W1 + (size_t)tid * 257;
  float s = b1[tid];
  #pragma unroll 4
  for (int k = 0; k < 256; ++k) s = fmaf(wr[k], inpS[k], s);
  out[(size_t)b * SLICE + tid] = s;
}

// out[b][t][o] = b2[o] + sum_m W2[o][m] * relu(base[b][m] + W1[m][256]*T[b][t])
extern "C" __global__ void __launch_bounds__(256)
mlp2_k(const float* __restrict__ T, const float* __restrict__ W1,
       const float* __restrict__ b2, const float* __restrict__ W2, float* out) {
  __shared__ float baseS[128], w1l[128], w2S[384];
  const int b = blockIdx.x, tid = threadIdx.x;
  if (tid < 128) {
    baseS[tid] = out[(size_t)b * SLICE + tid];   // read own slice BEFORE any write
    w1l[tid]   = W1[(size_t)tid * 257 + 256];
  }
  w2S[tid] = W2[tid];                            // 256 threads fill all 384
  if (tid < 128) w2S[256 + tid] = W2[256 + tid];
  __syncthreads();
  float x[4];
  #pragma unroll
  for (int q = 0; q < 4; ++q) x[q] = T[(size_t)b * TLEN + tid + q * 256];
  float a0[4], a1[4], a2[4];
  #pragma unroll
  for (int q = 0; q < 4; ++q) { a0[q] = b2[0]; a1[q] = b2[1]; a2[q] = b2[2]; }
  for (int mm = 0; mm < 128; ++mm) {
    float bm = baseS[mm], wl = w1l[mm];
    float w20 = w2S[mm], w21 = w2S[128 + mm], w22 = w2S[256 + mm];
    #pragma unroll
    for (int q = 0; q < 4; ++q) {
      float hv = fmaxf(fmaf(wl, x[q], bm), 0.0f);
      a0[q] = fmaf(w20, hv, a0[q]);
      a1[q] = fmaf(w21, hv, a1[q]);
      a2[q] = fmaf(w22, hv, a2[q]);
    }
  }
  #pragma unroll
  for (int q = 0; q < 4; ++q) {
    float* o = out + ((size_t)b * TLEN + tid + q * 256) * 3;
    o[0] = a0[q]; o[1] = a1[q]; o[2] = a2[q];
  }
}

extern "C" void kernel_launch(void* const* d_in, const int* in_sizes, int n_in,
                              void* d_out, int out_size, void* d_ws, size_t ws_size,
                              hipStream_t stream) {
  (void)in_sizes; (void)n_in; (void)out_size; (void)d_ws; (void)ws_size;
  const float* X1   = (const float*)d_in[0];
  const float* X2   = (const float*)d_in[1];
  const float* T    = (const float*)d_in[2];
  const float* W1m  = (const float*)d_in[3];
  const float* b1m  = (const float*)d_in[4];
  const float* Wih0 = (const float*)d_in[5];
  const float* Whh0 = (const float*)d_in[6];
  const float* bih0 = (const float*)d_in[7];
  const float* bhh0 = (const float*)d_in[8];
  const float* Wih1 = (const float*)d_in[9];
  const float* Whh1 = (const float*)d_in[10];
  const float* bih1 = (const float*)d_in[11];
  const float* bhh1 = (const float*)d_in[12];
  const float* W1p  = (const float*)d_in[13];
  const float* b1p  = (const float*)d_in[14];
  const float* W2p  = (const float*)d_in[15];
  const float* b2p  = (const float*)d_in[16];

  float* out = (float*)d_out;

  // flags must start at 0 every call
  hipMemsetAsync((char*)d_out + (size_t)FLAGF * 4, 0, 65536, stream);

  prep_t<<<dim3(896), dim3(256), 0, stream>>>(Wih0, Whh0, Wih1, Whh1, (__half*)out);

  lstm_pair<<<dim3(2 * NPAIR), dim3(NTHR), 0, stream>>>(X1, X2, W1m, b1m,
                                                        bih0, bhh0, bih1, bhh1,
                                                        out, out);

  mlp2_pre<<<dim3(256), dim3(128), 0, stream>>>(W1p, b1p, out);
  mlp2_k<<<dim3(256), dim3(256), 0, stream>>>(T, W1p, b2p, W2p, out);
}